// Round 2
// baseline (1108.243 us; speedup 1.0000x reference)
//
#include <hip/hip_runtime.h>

#define NN 50000
#define NE 800000
#define FDIM 256
#define NPB 16

typedef __attribute__((ext_vector_type(8))) short short8v;
typedef __attribute__((ext_vector_type(4))) float float4v;

__device__ __forceinline__ unsigned short f2bf(float f) {
  unsigned u = __float_as_uint(f);
  unsigned r = (u + 0x7fffu + ((u >> 16) & 1u)) >> 16;
  return (unsigned short)r;
}
__device__ __forceinline__ float bf2f(unsigned short b) {
  return __uint_as_float(((unsigned)b) << 16);
}

// ---------------- CSR build ----------------

__global__ __launch_bounds__(256) void k_hist(const int* __restrict__ dst, int* __restrict__ deg) {
  int e = blockIdx.x * 256 + threadIdx.x;
  if (e < NE) atomicAdd(&deg[dst[e]], 1);
}

__global__ __launch_bounds__(1024) void k_scan(const int* __restrict__ deg, int* __restrict__ offs,
                                               int* __restrict__ fillp) {
  __shared__ int wsum[16];
  __shared__ int s_carry;
  const int tid = threadIdx.x;
  const int lane = tid & 63;
  const int w = tid >> 6;
  if (tid == 0) s_carry = 0;
  __syncthreads();
  for (int base = 0; base < NN; base += 1024) {
    int i = base + tid;
    int v = (i < NN) ? deg[i] : 0;
    int incl = v;
    #pragma unroll
    for (int off = 1; off < 64; off <<= 1) {
      int tmp = __shfl_up(incl, off, 64);
      if (lane >= off) incl += tmp;
    }
    if (lane == 63) wsum[w] = incl;
    __syncthreads();
    if (w == 0 && lane < 16) {
      int s = wsum[lane];
      #pragma unroll
      for (int off = 1; off < 16; off <<= 1) {
        int tmp = __shfl_up(s, off, 64);
        if (lane >= off) s += tmp;
      }
      wsum[lane] = s;
    }
    __syncthreads();
    int carry = s_carry;
    int woff = (w == 0) ? 0 : wsum[w - 1];
    if (i < NN) {
      int excl = carry + woff + incl - v;
      offs[i] = excl;
      fillp[i] = excl;
    }
    __syncthreads();
    if (tid == 0) s_carry = carry + wsum[15];
    __syncthreads();
  }
  if (threadIdx.x == 0) offs[NN] = s_carry;
}

__global__ __launch_bounds__(256) void k_fill(const int* __restrict__ src, const int* __restrict__ dstA,
                                              int* __restrict__ fillp, int2* __restrict__ pairs) {
  int e = blockIdx.x * 256 + threadIdx.x;
  if (e < NE) {
    int d = dstA[e];
    int pos = atomicAdd(&fillp[d], 1);
    pairs[pos] = make_int2(src[e], e);
  }
}

// flatten: srcp[pos], wperm[pos] = {ew[0][eid], ew[1][eid], ew[2][eid], ew[3][eid]}
__global__ __launch_bounds__(256) void k_perm(const int2* __restrict__ pairs, const float* __restrict__ ew,
                                              int* __restrict__ srcp, float4* __restrict__ wperm) {
  int pos = blockIdx.x * 256 + threadIdx.x;
  if (pos < NE) {
    int2 pr = pairs[pos];
    srcp[pos] = pr.x;
    wperm[pos] = make_float4(ew[pr.y], ew[NE + pr.y], ew[2 * NE + pr.y], ew[3 * NE + pr.y]);
  }
}

// ---------------- weight / input prep (fp32 -> bf16, transposed) ----------------

// Bt1[t][k] = W1_0[c][k][j]; BtE[t][k] = encW[k][t]; Bt2[t][k] = blockdiag W1_1
__global__ __launch_bounds__(256) void k_wprep(const float* __restrict__ W1_0, const float* __restrict__ encW,
                                               const float* __restrict__ W1_1, unsigned short* __restrict__ Bt1,
                                               unsigned short* __restrict__ BtE, unsigned short* __restrict__ Bt2) {
  const int t = blockIdx.x;   // 0..255 output col
  const int k = threadIdx.x;  // 0..255 reduction dim
  const int c = t >> 6, j = t & 63;
  Bt1[t * 256 + k] = f2bf(W1_0[c * 16384 + k * 64 + j]);
  BtE[t * 256 + k] = f2bf(encW[k * 256 + t]);
  Bt2[t * 256 + k] = ((k >> 6) == c) ? f2bf(W1_1[c * 4096 + (k & 63) * 64 + j]) : (unsigned short)0;
}

__global__ __launch_bounds__(256) void k_xprep(const float* __restrict__ x, unsigned short* __restrict__ xb) {
  int idx = blockIdx.x * 256 + threadIdx.x;  // float4 index
  if (idx < NN * 64) {
    float4 v = reinterpret_cast<const float4*>(x)[idx];
    ushort4 o;
    o.x = f2bf(v.x); o.y = f2bf(v.y); o.z = f2bf(v.z); o.w = f2bf(v.w);
    reinterpret_cast<ushort4*>(xb)[idx] = o;
  }
}

// ---------------- MFMA GEMM: C[i][t] = sum_k A[i][k]*Bt[t][k] (+bias) ----------------
// A: [NN][256] bf16 row-major; Bt: [256][256] bf16 N-major. Block: 64 rows x 256 cols, 4 waves.
template <int OUT_BF16, int ADD_BIAS>
__global__ __launch_bounds__(256) void k_mm(const unsigned short* __restrict__ A,
                                            const unsigned short* __restrict__ Bt,
                                            const float* __restrict__ bias, void* __restrict__ Cout) {
  const int lane = threadIdx.x & 63;
  const int w = threadIdx.x >> 6;
  const int row0 = blockIdx.x * 64;
  const int colw = w * 64;
  const int lr = lane & 15;
  const int lk = (lane >> 4) * 8;

  const unsigned short* Aptr[4];
  const unsigned short* Bptr[4];
  #pragma unroll
  for (int rt = 0; rt < 4; rt++) {
    int row = row0 + rt * 16 + lr;
    if (row >= NN) row = NN - 1;  // clamp: value unused (epilogue guards), stay in-bounds
    Aptr[rt] = A + (size_t)row * 256 + lk;
  }
  #pragma unroll
  for (int ct = 0; ct < 4; ct++) Bptr[ct] = Bt + (size_t)(colw + ct * 16 + lr) * 256 + lk;

  float4v acc[4][4];
  #pragma unroll
  for (int rt = 0; rt < 4; rt++)
    #pragma unroll
    for (int ct = 0; ct < 4; ct++) acc[rt][ct] = (float4v){0.f, 0.f, 0.f, 0.f};

  for (int ks = 0; ks < 256; ks += 32) {
    short8v a[4], b[4];
    #pragma unroll
    for (int rt = 0; rt < 4; rt++) a[rt] = *reinterpret_cast<const short8v*>(Aptr[rt] + ks);
    #pragma unroll
    for (int ct = 0; ct < 4; ct++) b[ct] = *reinterpret_cast<const short8v*>(Bptr[ct] + ks);
    #pragma unroll
    for (int rt = 0; rt < 4; rt++)
      #pragma unroll
      for (int ct = 0; ct < 4; ct++)
        acc[rt][ct] = __builtin_amdgcn_mfma_f32_16x16x32_bf16(a[rt], b[ct], acc[rt][ct], 0, 0, 0);
  }

  #pragma unroll
  for (int rt = 0; rt < 4; rt++) {
    #pragma unroll
    for (int ct = 0; ct < 4; ct++) {
      const int col = colw + ct * 16 + lr;
      const float bv = ADD_BIAS ? bias[col] : 0.f;
      #pragma unroll
      for (int r = 0; r < 4; r++) {
        const int row = row0 + rt * 16 + (lane >> 4) * 4 + r;
        if (row < NN) {
          float v = acc[rt][ct][r] + bv;
          if (OUT_BF16)
            ((unsigned short*)Cout)[(size_t)row * 256 + col] = f2bf(v);
          else
            ((float*)Cout)[(size_t)row * 256 + col] = v;
        }
      }
    }
  }
}

// ---------------- fused aggregation + MLP(K=64) + BN stats ----------------
__global__ __launch_bounds__(256) void k_agg_mlp(const unsigned short* __restrict__ P,
                                                 const int* __restrict__ offs, const int* __restrict__ srcp,
                                                 const float4* __restrict__ wperm, const float* __restrict__ b1,
                                                 const float* __restrict__ W2, const float* __restrict__ b2,
                                                 float* __restrict__ Z, float* __restrict__ bnsum,
                                                 float* __restrict__ bnsq) {
  __shared__ __align__(16) float r_lds[256];
  const int t = threadIdx.x;
  const int c = t >> 6, j = t & 63;
  const float b1t = b1[t], b2t = b2[t];
  float w2col[64];
  #pragma unroll
  for (int m = 0; m < 64; m++) w2col[m] = W2[c * 4096 + m * 64 + j];
  float lsum = 0.f, lsq = 0.f;
  const int i0 = blockIdx.x * NPB;
  for (int ii = 0; ii < NPB; ii++) {
    const int i = i0 + ii;
    const int es = offs[i], ee = offs[i + 1];
    float acc = 0.f;
    for (int e = es; e < ee; e += 8) {
      int sidx[8];
      float wv[8];
      unsigned short pv[8];
      #pragma unroll
      for (int q = 0; q < 8; q++) sidx[q] = (e + q < ee) ? srcp[e + q] : -1;
      #pragma unroll
      for (int q = 0; q < 8; q++) {
        if (sidx[q] >= 0) {
          float4 w4 = wperm[e + q];
          wv[q] = (c == 0) ? w4.x : (c == 1) ? w4.y : (c == 2) ? w4.z : w4.w;
          pv[q] = P[(size_t)sidx[q] * 256 + t];
        } else {
          wv[q] = 0.f;
          pv[q] = 0;
        }
      }
      #pragma unroll
      for (int q = 0; q < 8; q++) acc = fmaf(wv[q], bf2f(pv[q]), acc);
    }
    float r = bf2f(P[(size_t)i * 256 + t]) + acc + b1t;
    r = r > 0.f ? r : 0.f;
    __syncthreads();
    r_lds[t] = r;
    __syncthreads();
    float z = b2t;
    #pragma unroll
    for (int m4 = 0; m4 < 16; m4++) {
      float4 rv = *reinterpret_cast<const float4*>(&r_lds[c * 64 + m4 * 4]);
      z = fmaf(rv.x, w2col[m4 * 4 + 0], z);
      z = fmaf(rv.y, w2col[m4 * 4 + 1], z);
      z = fmaf(rv.z, w2col[m4 * 4 + 2], z);
      z = fmaf(rv.w, w2col[m4 * 4 + 3], z);
    }
    Z[(size_t)i * 256 + t] = z;
    lsum += z;
    lsq += z * z;
  }
  atomicAdd(&bnsum[t], lsum);
  atomicAdd(&bnsq[t], lsq);
}

// ---------------- BN affine + relu (in place) + optional bf16 copy ----------------
__global__ __launch_bounds__(256) void k_bn_apply(float* __restrict__ Z, unsigned short* __restrict__ Hb,
                                                  const float* __restrict__ bnsum, const float* __restrict__ bnsq,
                                                  const float* __restrict__ g, const float* __restrict__ bt) {
  __shared__ __align__(16) float s_scale[256], s_shift[256];
  const int t = threadIdx.x;
  {
    float mu = bnsum[t] * (1.f / NN);
    float var = bnsq[t] * (1.f / NN) - mu * mu;
    var = var > 0.f ? var : 0.f;
    float rs = rsqrtf(var + 1e-5f);
    float sc = g[t] * rs;
    s_scale[t] = sc;
    s_shift[t] = bt[t] - mu * sc;
  }
  __syncthreads();
  const int idx0 = blockIdx.x * 256 + t;
  const float4 sc4 = reinterpret_cast<const float4*>(s_scale)[idx0 & 63];
  const float4 sh4 = reinterpret_cast<const float4*>(s_shift)[idx0 & 63];
  const int total4 = NN * 64;
  for (int idx = idx0; idx < total4; idx += gridDim.x * 256) {
    float4 z = reinterpret_cast<float4*>(Z)[idx];
    float4 h;
    h.x = fmaxf(fmaf(z.x, sc4.x, sh4.x), 0.f);
    h.y = fmaxf(fmaf(z.y, sc4.y, sh4.y), 0.f);
    h.z = fmaxf(fmaf(z.z, sc4.z, sh4.z), 0.f);
    h.w = fmaxf(fmaf(z.w, sc4.w, sh4.w), 0.f);
    reinterpret_cast<float4*>(Z)[idx] = h;
    if (Hb) {
      ushort4 hb;
      hb.x = f2bf(h.x); hb.y = f2bf(h.y); hb.z = f2bf(h.z); hb.w = f2bf(h.w);
      reinterpret_cast<ushort4*>(Hb)[idx] = hb;
    }
  }
}

// ---------------- launch ----------------

extern "C" void kernel_launch(void* const* d_in, const int* in_sizes, int n_in,
                              void* d_out, int out_size, void* d_ws, size_t ws_size,
                              hipStream_t stream) {
  const float* x    = (const float*)d_in[0];
  const int*   ei   = (const int*)d_in[1];
  const float* ew   = (const float*)d_in[2];
  const float* W1_0 = (const float*)d_in[3];
  const float* b1_0 = (const float*)d_in[4];
  const float* W2_0 = (const float*)d_in[5];
  const float* b2_0 = (const float*)d_in[6];
  const float* g0   = (const float*)d_in[7];
  const float* bt0  = (const float*)d_in[8];
  const float* W1_1 = (const float*)d_in[9];
  const float* b1_1 = (const float*)d_in[10];
  const float* W2_1 = (const float*)d_in[11];
  const float* b2_1 = (const float*)d_in[12];
  const float* g1   = (const float*)d_in[13];
  const float* bt1  = (const float*)d_in[14];
  const float* encW = (const float*)d_in[15];
  const float* encb = (const float*)d_in[16];

  const int* srcA = ei;
  const int* dstA = ei + NE;

  float* out_enc = (float*)d_out;
  float* out1 = out_enc + (size_t)NN * FDIM;
  float* out2 = out1 + (size_t)NN * FDIM;

  // P (bf16, layer1 & layer2) and H1b (bf16 h1) live inside the enc output
  // region (written last): 25.6MB + 25.6MB = 51.2MB exactly.
  unsigned short* Pbf = (unsigned short*)out_enc;
  unsigned short* H1b = Pbf + (size_t)NN * FDIM;

  char* wp = (char*)d_ws;
  auto carve = [&](size_t bytes) {
    char* r = wp;
    wp += (bytes + 255) & ~(size_t)255;
    return r;
  };
  int*   deg    = (int*)carve((size_t)NN * 4);
  int*   offs   = (int*)carve((size_t)(NN + 1) * 4);
  int*   fillp  = (int*)carve((size_t)NN * 4);
  int*   srcp   = (int*)carve((size_t)NE * 4);
  float4* wperm = (float4*)carve((size_t)NE * 16);
  float* bnsum0 = (float*)carve(256 * 4);
  float* bnsq0  = (float*)carve(256 * 4);
  float* bnsum1 = (float*)carve(256 * 4);
  float* bnsq1  = (float*)carve(256 * 4);
  unsigned short* Bt1 = (unsigned short*)carve(256 * 256 * 2);
  unsigned short* Bt2 = (unsigned short*)carve(256 * 256 * 2);
  unsigned short* BtE = (unsigned short*)carve(256 * 256 * 2);
  // region R: pairs (int2, 6.4MB) lives first, then xb (bf16 x, 25.6MB)
  // overwrites it after k_perm has consumed pairs.
  char* R = carve((size_t)NN * FDIM * 2);  // 25.6MB (>= pairs' 6.4MB)
  int2* pairs = (int2*)R;
  unsigned short* xb = (unsigned short*)R;

  hipMemsetAsync(deg, 0, (size_t)NN * 4, stream);
  hipMemsetAsync(bnsum0, 0, 4 * 1024, stream);  // bnsum0,bnsq0,bnsum1,bnsq1 contiguous

  // CSR + edge permutation
  k_hist<<<(NE + 255) / 256, 256, 0, stream>>>(dstA, deg);
  k_scan<<<1, 1024, 0, stream>>>(deg, offs, fillp);
  k_fill<<<(NE + 255) / 256, 256, 0, stream>>>(srcA, dstA, fillp, pairs);
  k_perm<<<(NE + 255) / 256, 256, 0, stream>>>(pairs, ew, srcp, wperm);

  // bf16 prep (xb overwrites pairs region - must follow k_perm)
  k_wprep<<<256, 256, 0, stream>>>(W1_0, encW, W1_1, Bt1, BtE, Bt2);
  k_xprep<<<(NN * 64 + 255) / 256, 256, 0, stream>>>(x, xb);

  const int MMG = (NN + 63) / 64;

  // layer 1
  k_mm<1, 0><<<MMG, 256, 0, stream>>>(xb, Bt1, nullptr, Pbf);
  k_agg_mlp<<<NN / NPB, 256, 0, stream>>>(Pbf, offs, srcp, wperm, b1_0, W2_0, b2_0, out1, bnsum0, bnsq0);
  k_bn_apply<<<2048, 256, 0, stream>>>(out1, H1b, bnsum0, bnsq0, g0, bt0);

  // layer 2
  k_mm<1, 0><<<MMG, 256, 0, stream>>>(H1b, Bt2, nullptr, Pbf);
  k_agg_mlp<<<NN / NPB, 256, 0, stream>>>(Pbf, offs, srcp, wperm, b1_1, W2_1, b2_1, out2, bnsum1, bnsq1);
  k_bn_apply<<<2048, 256, 0, stream>>>(out2, nullptr, bnsum1, bnsq1, g1, bt1);

  // encoder last (overwrites Pbf/H1b scratch with final enc output)
  k_mm<0, 1><<<MMG, 256, 0, stream>>>(xb, BtE, encb, out_enc);
}

// Round 3
// 556.769 us; speedup vs baseline: 1.9905x; 1.9905x over previous
//
#include <hip/hip_runtime.h>

#define NN 50000
#define NE 800000
#define FDIM 256

typedef __attribute__((ext_vector_type(8))) short short8v;
typedef __attribute__((ext_vector_type(4))) float float4v;

__device__ __forceinline__ unsigned short f2bf(float f) {
  unsigned u = __float_as_uint(f);
  unsigned r = (u + 0x7fffu + ((u >> 16) & 1u)) >> 16;
  return (unsigned short)r;
}
__device__ __forceinline__ float bf2f(unsigned short b) {
  return __uint_as_float(((unsigned)b) << 16);
}

// ---------------- CSR build ----------------

__global__ __launch_bounds__(256) void k_hist(const int* __restrict__ dst, int* __restrict__ deg) {
  int e = blockIdx.x * 256 + threadIdx.x;
  if (e < NE) atomicAdd(&deg[dst[e]], 1);
}

__global__ __launch_bounds__(1024) void k_scan(const int* __restrict__ deg, int* __restrict__ offs,
                                               int* __restrict__ fillp) {
  __shared__ int wsum[16];
  __shared__ int s_carry;
  const int tid = threadIdx.x;
  const int lane = tid & 63;
  const int w = tid >> 6;
  if (tid == 0) s_carry = 0;
  __syncthreads();
  for (int base = 0; base < NN; base += 1024) {
    int i = base + tid;
    int v = (i < NN) ? deg[i] : 0;
    int incl = v;
    #pragma unroll
    for (int off = 1; off < 64; off <<= 1) {
      int tmp = __shfl_up(incl, off, 64);
      if (lane >= off) incl += tmp;
    }
    if (lane == 63) wsum[w] = incl;
    __syncthreads();
    if (w == 0 && lane < 16) {
      int s = wsum[lane];
      #pragma unroll
      for (int off = 1; off < 16; off <<= 1) {
        int tmp = __shfl_up(s, off, 64);
        if (lane >= off) s += tmp;
      }
      wsum[lane] = s;
    }
    __syncthreads();
    int carry = s_carry;
    int woff = (w == 0) ? 0 : wsum[w - 1];
    if (i < NN) {
      int excl = carry + woff + incl - v;
      offs[i] = excl;
      fillp[i] = excl;
    }
    __syncthreads();
    if (tid == 0) s_carry = carry + wsum[15];
    __syncthreads();
  }
  if (threadIdx.x == 0) offs[NN] = s_carry;
}

__global__ __launch_bounds__(256) void k_fill(const int* __restrict__ src, const int* __restrict__ dstA,
                                              int* __restrict__ fillp, int2* __restrict__ pairs) {
  int e = blockIdx.x * 256 + threadIdx.x;
  if (e < NE) {
    int d = dstA[e];
    int pos = atomicAdd(&fillp[d], 1);
    pairs[pos] = make_int2(src[e], e);
  }
}

__global__ __launch_bounds__(256) void k_perm(const int2* __restrict__ pairs, const float* __restrict__ ew,
                                              int* __restrict__ srcp, float4* __restrict__ wperm) {
  int pos = blockIdx.x * 256 + threadIdx.x;
  if (pos < NE) {
    int2 pr = pairs[pos];
    srcp[pos] = pr.x;
    wperm[pos] = make_float4(ew[pr.y], ew[NE + pr.y], ew[2 * NE + pr.y], ew[3 * NE + pr.y]);
  }
}

// ---------------- weight / input prep (fp32 -> bf16) ----------------
// Bt1[t][k]=W1_0[c][k][j] (K=256 N-major); BtE[t][k]=encW[k][t];
// blockdiag N-major 64x64 tables: Wb[c*4096 + j*64 + k] = W[c][k][j]
__global__ __launch_bounds__(256) void k_wprep(const float* __restrict__ W1_0, const float* __restrict__ encW,
                                               const float* __restrict__ W1_1, const float* __restrict__ W2_0,
                                               const float* __restrict__ W2_1, unsigned short* __restrict__ Bt1,
                                               unsigned short* __restrict__ BtE, unsigned short* __restrict__ Wb11,
                                               unsigned short* __restrict__ Wb20, unsigned short* __restrict__ Wb21) {
  const int t = blockIdx.x;   // 0..255 output col
  const int k = threadIdx.x;  // 0..255 reduction index
  const int c = t >> 6, j = t & 63;
  Bt1[t * 256 + k] = f2bf(W1_0[c * 16384 + k * 64 + j]);
  BtE[t * 256 + k] = f2bf(encW[k * 256 + t]);
  if (k < 64) {
    Wb11[c * 4096 + j * 64 + k] = f2bf(W1_1[c * 4096 + k * 64 + j]);
    Wb20[c * 4096 + j * 64 + k] = f2bf(W2_0[c * 4096 + k * 64 + j]);
    Wb21[c * 4096 + j * 64 + k] = f2bf(W2_1[c * 4096 + k * 64 + j]);
  }
}

__global__ __launch_bounds__(256) void k_xprep(const float* __restrict__ x, unsigned short* __restrict__ xb) {
  int idx = blockIdx.x * 256 + threadIdx.x;  // float4 index
  if (idx < NN * 64) {
    float4 v = reinterpret_cast<const float4*>(x)[idx];
    ushort4 o;
    o.x = f2bf(v.x); o.y = f2bf(v.y); o.z = f2bf(v.z); o.w = f2bf(v.w);
    reinterpret_cast<ushort4*>(xb)[idx] = o;
  }
}

// ---------------- MFMA GEMM, K=256: C[i][t] = sum_k A[i][k]*Bt[t][k] (+bias) ----------------
template <int OUT_BF16, int ADD_BIAS>
__global__ __launch_bounds__(256) void k_mm(const unsigned short* __restrict__ A,
                                            const unsigned short* __restrict__ Bt,
                                            const float* __restrict__ bias, void* __restrict__ Cout) {
  const int lane = threadIdx.x & 63;
  const int w = threadIdx.x >> 6;
  const int row0 = blockIdx.x * 64;
  const int colw = w * 64;
  const int lr = lane & 15;
  const int lk = (lane >> 4) * 8;

  const unsigned short* Aptr[4];
  const unsigned short* Bptr[4];
  #pragma unroll
  for (int rt = 0; rt < 4; rt++) {
    int row = row0 + rt * 16 + lr;
    if (row >= NN) row = NN - 1;
    Aptr[rt] = A + (size_t)row * 256 + lk;
  }
  #pragma unroll
  for (int ct = 0; ct < 4; ct++) Bptr[ct] = Bt + (size_t)(colw + ct * 16 + lr) * 256 + lk;

  float4v acc[4][4];
  #pragma unroll
  for (int rt = 0; rt < 4; rt++)
    #pragma unroll
    for (int ct = 0; ct < 4; ct++) acc[rt][ct] = (float4v){0.f, 0.f, 0.f, 0.f};

  for (int ks = 0; ks < 256; ks += 32) {
    short8v a[4], b[4];
    #pragma unroll
    for (int rt = 0; rt < 4; rt++) a[rt] = *reinterpret_cast<const short8v*>(Aptr[rt] + ks);
    #pragma unroll
    for (int ct = 0; ct < 4; ct++) b[ct] = *reinterpret_cast<const short8v*>(Bptr[ct] + ks);
    #pragma unroll
    for (int rt = 0; rt < 4; rt++)
      #pragma unroll
      for (int ct = 0; ct < 4; ct++)
        acc[rt][ct] = __builtin_amdgcn_mfma_f32_16x16x32_bf16(a[rt], b[ct], acc[rt][ct], 0, 0, 0);
  }

  #pragma unroll
  for (int rt = 0; rt < 4; rt++) {
    #pragma unroll
    for (int ct = 0; ct < 4; ct++) {
      const int col = colw + ct * 16 + lr;
      const float bv = ADD_BIAS ? bias[col] : 0.f;
      #pragma unroll
      for (int r = 0; r < 4; r++) {
        const int row = row0 + rt * 16 + (lane >> 4) * 4 + r;
        if (row < NN) {
          float v = acc[rt][ct][r] + bv;
          if (OUT_BF16)
            ((unsigned short*)Cout)[(size_t)row * 256 + col] = f2bf(v);
          else
            ((float*)Cout)[(size_t)row * 256 + col] = v;
        }
      }
    }
  }
}

// ---------------- MFMA block-diagonal GEMM, K=64 per community ----------------
// C[i][64c+j] = sum_m A[i][64c+m] * W[c][m][j] (+bias) ; optional BN partial sums.
template <int OUT_BF16, int ADD_BIAS, int BN_STATS>
__global__ __launch_bounds__(256) void k_bd(const unsigned short* __restrict__ A,
                                            const unsigned short* __restrict__ Wb,  // [c][j][k] N-major
                                            const float* __restrict__ bias, void* __restrict__ Cout,
                                            float* __restrict__ bnsum, float* __restrict__ bnsq) {
  const int lane = threadIdx.x & 63;
  const int w = threadIdx.x >> 6;  // community
  const int row0 = blockIdx.x * 64;
  const int lr = lane & 15;
  const int lk = (lane >> 4) * 8;

  const unsigned short* Aptr[4];
  #pragma unroll
  for (int rt = 0; rt < 4; rt++) {
    int row = row0 + rt * 16 + lr;
    if (row >= NN) row = NN - 1;
    Aptr[rt] = A + (size_t)row * 256 + w * 64 + lk;
  }

  float4v acc[4][4];
  #pragma unroll
  for (int rt = 0; rt < 4; rt++)
    #pragma unroll
    for (int ct = 0; ct < 4; ct++) acc[rt][ct] = (float4v){0.f, 0.f, 0.f, 0.f};

  #pragma unroll
  for (int ks = 0; ks < 64; ks += 32) {
    short8v a[4], b[4];
    #pragma unroll
    for (int rt = 0; rt < 4; rt++) a[rt] = *reinterpret_cast<const short8v*>(Aptr[rt] + ks);
    #pragma unroll
    for (int ct = 0; ct < 4; ct++)
      b[ct] = *reinterpret_cast<const short8v*>(Wb + (size_t)w * 4096 + (ct * 16 + lr) * 64 + ks + lk);
    #pragma unroll
    for (int rt = 0; rt < 4; rt++)
      #pragma unroll
      for (int ct = 0; ct < 4; ct++)
        acc[rt][ct] = __builtin_amdgcn_mfma_f32_16x16x32_bf16(a[rt], b[ct], acc[rt][ct], 0, 0, 0);
  }

  #pragma unroll
  for (int ct = 0; ct < 4; ct++) {
    const int col = w * 64 + ct * 16 + lr;
    const float bv = ADD_BIAS ? bias[col] : 0.f;
    float s1 = 0.f, s2 = 0.f;
    #pragma unroll
    for (int rt = 0; rt < 4; rt++) {
      #pragma unroll
      for (int r = 0; r < 4; r++) {
        const int row = row0 + rt * 16 + (lane >> 4) * 4 + r;
        if (row < NN) {
          float v = acc[rt][ct][r] + bv;
          if (OUT_BF16)
            ((unsigned short*)Cout)[(size_t)row * 256 + col] = f2bf(v);
          else
            ((float*)Cout)[(size_t)row * 256 + col] = v;
          if (BN_STATS) { s1 += v; s2 += v * v; }
        }
      }
    }
    if (BN_STATS) {
      s1 += __shfl_xor(s1, 16); s1 += __shfl_xor(s1, 32);
      s2 += __shfl_xor(s2, 16); s2 += __shfl_xor(s2, 32);
      if (lane < 16) {
        atomicAdd(&bnsum[col], s1);
        atomicAdd(&bnsq[col], s2);
      }
    }
  }
}

// ---------------- aggregation: one wave per node, barrier-free ----------------
// Rb[i][t] = bf16( relu( P[i][t] + sum_e w_e*P[src_e][t] + b1[t] ) )
__global__ __launch_bounds__(256) void k_agg(const unsigned short* __restrict__ P,
                                             const int* __restrict__ offs, const int* __restrict__ srcp,
                                             const float4* __restrict__ wperm, const float* __restrict__ b1,
                                             unsigned short* __restrict__ Rb) {
  const int lane = threadIdx.x & 63;
  const int wid = threadIdx.x >> 6;
  const int i = blockIdx.x * 4 + wid;  // grid = NN/4 exactly
  const int half = lane >> 5;          // 0: even edges, 1: odd edges
  const int l32 = lane & 31;
  const int col0 = l32 * 8;            // 8 bf16 columns per lane
  const int c = l32 >> 3;              // community of this lane's columns

  const int es = offs[i], ee = offs[i + 1];
  float acc[8];
  #pragma unroll
  for (int j = 0; j < 8; j++) acc[j] = 0.f;

  for (int base = es; base < ee; base += 8) {
    int sq[4];
    float wq[4];
    #pragma unroll
    for (int q = 0; q < 4; q++) {
      int e = base + 2 * q + half;
      bool valid = e < ee;
      int ec = valid ? e : (NE - 1);
      sq[q] = srcp[ec];
      float4 w4 = wperm[ec];
      float wv = (c == 0) ? w4.x : (c == 1) ? w4.y : (c == 2) ? w4.z : w4.w;
      wq[q] = valid ? wv : 0.f;
    }
    short8v pq[4];
    #pragma unroll
    for (int q = 0; q < 4; q++)
      pq[q] = *reinterpret_cast<const short8v*>(P + (size_t)sq[q] * 256 + col0);
    #pragma unroll
    for (int q = 0; q < 4; q++)
      #pragma unroll
      for (int j = 0; j < 8; j++)
        acc[j] = fmaf(wq[q], bf2f((unsigned short)pq[q][j]), acc[j]);
  }

  #pragma unroll
  for (int j = 0; j < 8; j++) acc[j] += __shfl_xor(acc[j], 32);

  if (half == 0) {
    short8v ps = *reinterpret_cast<const short8v*>(P + (size_t)i * 256 + col0);
    float4 b4a = *reinterpret_cast<const float4*>(b1 + col0);
    float4 b4b = *reinterpret_cast<const float4*>(b1 + col0 + 4);
    float bb[8] = {b4a.x, b4a.y, b4a.z, b4a.w, b4b.x, b4b.y, b4b.z, b4b.w};
    short8v out;
    #pragma unroll
    for (int j = 0; j < 8; j++) {
      float r = bf2f((unsigned short)ps[j]) + acc[j] + bb[j];
      out[j] = (short)f2bf(r > 0.f ? r : 0.f);
    }
    *reinterpret_cast<short8v*>(Rb + (size_t)i * 256 + col0) = out;
  }
}

// ---------------- BN affine + relu (in place) + optional bf16 copy ----------------
__global__ __launch_bounds__(256) void k_bn_apply(float* __restrict__ Z, unsigned short* __restrict__ Hb,
                                                  const float* __restrict__ bnsum, const float* __restrict__ bnsq,
                                                  const float* __restrict__ g, const float* __restrict__ bt) {
  __shared__ __align__(16) float s_scale[256], s_shift[256];
  const int t = threadIdx.x;
  {
    float mu = bnsum[t] * (1.f / NN);
    float var = bnsq[t] * (1.f / NN) - mu * mu;
    var = var > 0.f ? var : 0.f;
    float rs = rsqrtf(var + 1e-5f);
    float sc = g[t] * rs;
    s_scale[t] = sc;
    s_shift[t] = bt[t] - mu * sc;
  }
  __syncthreads();
  const int idx0 = blockIdx.x * 256 + t;
  const float4 sc4 = reinterpret_cast<const float4*>(s_scale)[idx0 & 63];
  const float4 sh4 = reinterpret_cast<const float4*>(s_shift)[idx0 & 63];
  const int total4 = NN * 64;
  for (int idx = idx0; idx < total4; idx += gridDim.x * 256) {
    float4 z = reinterpret_cast<float4*>(Z)[idx];
    float4 h;
    h.x = fmaxf(fmaf(z.x, sc4.x, sh4.x), 0.f);
    h.y = fmaxf(fmaf(z.y, sc4.y, sh4.y), 0.f);
    h.z = fmaxf(fmaf(z.z, sc4.z, sh4.z), 0.f);
    h.w = fmaxf(fmaf(z.w, sc4.w, sh4.w), 0.f);
    reinterpret_cast<float4*>(Z)[idx] = h;
    if (Hb) {
      ushort4 hb;
      hb.x = f2bf(h.x); hb.y = f2bf(h.y); hb.z = f2bf(h.z); hb.w = f2bf(h.w);
      reinterpret_cast<ushort4*>(Hb)[idx] = hb;
    }
  }
}

// ---------------- launch ----------------

extern "C" void kernel_launch(void* const* d_in, const int* in_sizes, int n_in,
                              void* d_out, int out_size, void* d_ws, size_t ws_size,
                              hipStream_t stream) {
  const float* x    = (const float*)d_in[0];
  const int*   ei   = (const int*)d_in[1];
  const float* ew   = (const float*)d_in[2];
  const float* W1_0 = (const float*)d_in[3];
  const float* b1_0 = (const float*)d_in[4];
  const float* W2_0 = (const float*)d_in[5];
  const float* b2_0 = (const float*)d_in[6];
  const float* g0   = (const float*)d_in[7];
  const float* bt0  = (const float*)d_in[8];
  const float* W1_1 = (const float*)d_in[9];
  const float* b1_1 = (const float*)d_in[10];
  const float* W2_1 = (const float*)d_in[11];
  const float* b2_1 = (const float*)d_in[12];
  const float* g1   = (const float*)d_in[13];
  const float* bt1  = (const float*)d_in[14];
  const float* encW = (const float*)d_in[15];
  const float* encb = (const float*)d_in[16];

  const int* srcA = ei;
  const int* dstA = ei + NE;

  float* out_enc = (float*)d_out;
  float* out1 = out_enc + (size_t)NN * FDIM;
  float* out2 = out1 + (size_t)NN * FDIM;

  // enc output region (written last) hosts: Pbf (25.6MB) + H1b/Rb2 (25.6MB).
  unsigned short* Pbf = (unsigned short*)out_enc;
  unsigned short* H1b = Pbf + (size_t)NN * FDIM;
  unsigned short* Rb2 = H1b;  // reuses H1b region after H1b is consumed
  // out2 region (written by layer-2 k_bd) hosts layer-1 r (bf16) until then.
  unsigned short* Rb1 = (unsigned short*)out2;

  char* wp = (char*)d_ws;
  auto carve = [&](size_t bytes) {
    char* r = wp;
    wp += (bytes + 255) & ~(size_t)255;
    return r;
  };
  int*   deg    = (int*)carve((size_t)NN * 4);
  int*   offs   = (int*)carve((size_t)(NN + 1) * 4);
  int*   fillp  = (int*)carve((size_t)NN * 4);
  int*   srcp   = (int*)carve((size_t)NE * 4);
  float4* wperm = (float4*)carve((size_t)NE * 16);
  float* bnsum0 = (float*)carve(256 * 4);
  float* bnsq0  = (float*)carve(256 * 4);
  float* bnsum1 = (float*)carve(256 * 4);
  float* bnsq1  = (float*)carve(256 * 4);
  unsigned short* Bt1  = (unsigned short*)carve(256 * 256 * 2);
  unsigned short* BtE  = (unsigned short*)carve(256 * 256 * 2);
  unsigned short* Wb11 = (unsigned short*)carve(4 * 64 * 64 * 2);
  unsigned short* Wb20 = (unsigned short*)carve(4 * 64 * 64 * 2);
  unsigned short* Wb21 = (unsigned short*)carve(4 * 64 * 64 * 2);
  // region R: pairs (int2, 6.4MB) first, then xb (bf16 x, 25.6MB) overwrites
  // it after k_perm has consumed pairs.
  char* R = carve((size_t)NN * FDIM * 2);
  int2* pairs = (int2*)R;
  unsigned short* xb = (unsigned short*)R;

  hipMemsetAsync(deg, 0, (size_t)NN * 4, stream);
  hipMemsetAsync(bnsum0, 0, 4 * 1024, stream);  // bnsum0,bnsq0,bnsum1,bnsq1 contiguous

  // CSR + edge permutation
  k_hist<<<(NE + 255) / 256, 256, 0, stream>>>(dstA, deg);
  k_scan<<<1, 1024, 0, stream>>>(deg, offs, fillp);
  k_fill<<<(NE + 255) / 256, 256, 0, stream>>>(srcA, dstA, fillp, pairs);
  k_perm<<<(NE + 255) / 256, 256, 0, stream>>>(pairs, ew, srcp, wperm);

  // bf16 prep (xb overwrites pairs region - must follow k_perm)
  k_wprep<<<256, 256, 0, stream>>>(W1_0, encW, W1_1, W2_0, W2_1, Bt1, BtE, Wb11, Wb20, Wb21);
  k_xprep<<<(NN * 64 + 255) / 256, 256, 0, stream>>>(x, xb);

  const int MMG = (NN + 63) / 64;

  // layer 1
  k_mm<1, 0><<<MMG, 256, 0, stream>>>(xb, Bt1, nullptr, Pbf);
  k_agg<<<NN / 4, 256, 0, stream>>>(Pbf, offs, srcp, wperm, b1_0, Rb1);
  k_bd<0, 1, 1><<<MMG, 256, 0, stream>>>(Rb1, Wb20, b2_0, out1, bnsum0, bnsq0);
  k_bn_apply<<<2048, 256, 0, stream>>>(out1, H1b, bnsum0, bnsq0, g0, bt0);

  // layer 2
  k_bd<1, 0, 0><<<MMG, 256, 0, stream>>>(H1b, Wb11, nullptr, Pbf, nullptr, nullptr);
  k_agg<<<NN / 4, 256, 0, stream>>>(Pbf, offs, srcp, wperm, b1_1, Rb2);
  k_bd<0, 1, 1><<<MMG, 256, 0, stream>>>(Rb2, Wb21, b2_1, out2, bnsum1, bnsq1);
  k_bn_apply<<<2048, 256, 0, stream>>>(out2, nullptr, bnsum1, bnsq1, g1, bt1);

  // encoder last (overwrites Pbf/Rb2 scratch with final enc output)
  k_mm<0, 1><<<MMG, 256, 0, stream>>>(xb, BtE, encb, out_enc);
}

// Round 4
// 436.294 us; speedup vs baseline: 2.5401x; 1.2761x over previous
//
#include <hip/hip_runtime.h>

#define NN 50000
#define NE 800000
#define FDIM 256
#define SCAN_BLOCKS 196  // ceil(50000/256)

typedef __attribute__((ext_vector_type(8))) short short8v;
typedef __attribute__((ext_vector_type(4))) float float4v;

__device__ __forceinline__ unsigned short f2bf(float f) {
  unsigned u = __float_as_uint(f);
  unsigned r = (u + 0x7fffu + ((u >> 16) & 1u)) >> 16;
  return (unsigned short)r;
}
__device__ __forceinline__ float bf2f(unsigned short b) {
  return __uint_as_float(((unsigned)b) << 16);
}

// ---------------- CSR build ----------------

__global__ __launch_bounds__(256) void k_hist(const int* __restrict__ dst, int* __restrict__ deg) {
  int e = blockIdx.x * 256 + threadIdx.x;
  if (e < NE) atomicAdd(&deg[dst[e]], 1);
}

__device__ __forceinline__ int block_incl_scan(int v, int* wsum) {
  const int tid = threadIdx.x;
  const int lane = tid & 63;
  const int w = tid >> 6;
  int incl = v;
  #pragma unroll
  for (int off = 1; off < 64; off <<= 1) {
    int tmp = __shfl_up(incl, off, 64);
    if (lane >= off) incl += tmp;
  }
  if (lane == 63) wsum[w] = incl;
  __syncthreads();
  int woff = 0;
  #pragma unroll
  for (int k = 0; k < 3; k++)
    if (k < w) woff += wsum[k];
  return woff + incl;
}

__global__ __launch_bounds__(256) void k_scan_a(const int* __restrict__ deg, int* __restrict__ partial) {
  __shared__ int wsum[4];
  int i = blockIdx.x * 256 + threadIdx.x;
  int v = (i < NN) ? deg[i] : 0;
  int incl = block_incl_scan(v, wsum);
  if (threadIdx.x == 255) partial[blockIdx.x] = incl;
}

__global__ __launch_bounds__(256) void k_scan_b(int* __restrict__ partial, int* __restrict__ offs) {
  __shared__ int wsum[4];
  int tid = threadIdx.x;
  int v = (tid < SCAN_BLOCKS) ? partial[tid] : 0;
  int incl = block_incl_scan(v, wsum);
  if (tid < SCAN_BLOCKS) partial[tid] = incl - v;  // exclusive
  if (tid == 255) offs[NN] = incl;                 // total == NE
}

__global__ __launch_bounds__(256) void k_scan_c(const int* __restrict__ deg, const int* __restrict__ partial,
                                                int* __restrict__ offs, int* __restrict__ fillp) {
  __shared__ int wsum[4];
  int i = blockIdx.x * 256 + threadIdx.x;
  int v = (i < NN) ? deg[i] : 0;
  int incl = block_incl_scan(v, wsum);
  int excl = partial[blockIdx.x] + incl - v;
  if (i < NN) {
    offs[i] = excl;
    fillp[i] = excl;
  }
}

// fill CSR slots directly with src id and the 4 community weights (one pass)
__global__ __launch_bounds__(256) void k_fillperm(const int* __restrict__ src, const int* __restrict__ dstA,
                                                  const float* __restrict__ ew, int* __restrict__ fillp,
                                                  int* __restrict__ srcp, float4* __restrict__ wperm) {
  int e = blockIdx.x * 256 + threadIdx.x;
  if (e < NE) {
    int d = dstA[e];
    int s = src[e];
    float4 w4 = make_float4(ew[e], ew[NE + e], ew[2 * NE + e], ew[3 * NE + e]);
    int pos = atomicAdd(&fillp[d], 1);
    srcp[pos] = s;
    wperm[pos] = w4;
  }
}

// ---------------- weight / input prep (fp32 -> bf16) ----------------
__global__ __launch_bounds__(256) void k_wprep(const float* __restrict__ W1_0, const float* __restrict__ encW,
                                               const float* __restrict__ W1_1, const float* __restrict__ W2_0,
                                               const float* __restrict__ W2_1, unsigned short* __restrict__ Bt1,
                                               unsigned short* __restrict__ BtE, unsigned short* __restrict__ Wb11,
                                               unsigned short* __restrict__ Wb20, unsigned short* __restrict__ Wb21) {
  const int t = blockIdx.x;   // output col
  const int k = threadIdx.x;  // reduction index
  const int c = t >> 6, j = t & 63;
  Bt1[t * 256 + k] = f2bf(W1_0[c * 16384 + k * 64 + j]);
  BtE[t * 256 + k] = f2bf(encW[k * 256 + t]);
  if (k < 64) {
    Wb11[c * 4096 + j * 64 + k] = f2bf(W1_1[c * 4096 + k * 64 + j]);
    Wb20[c * 4096 + j * 64 + k] = f2bf(W2_0[c * 4096 + k * 64 + j]);
    Wb21[c * 4096 + j * 64 + k] = f2bf(W2_1[c * 4096 + k * 64 + j]);
  }
}

__global__ __launch_bounds__(256) void k_xprep(const float* __restrict__ x, unsigned short* __restrict__ xb) {
  int idx = blockIdx.x * 256 + threadIdx.x;  // float4 index
  if (idx < NN * 64) {
    float4 v = reinterpret_cast<const float4*>(x)[idx];
    ushort4 o;
    o.x = f2bf(v.x); o.y = f2bf(v.y); o.z = f2bf(v.z); o.w = f2bf(v.w);
    reinterpret_cast<ushort4*>(xb)[idx] = o;
  }
}

// ---------------- MFMA GEMM, K=256 ----------------
template <int OUT_BF16, int ADD_BIAS>
__global__ __launch_bounds__(256) void k_mm(const unsigned short* __restrict__ A,
                                            const unsigned short* __restrict__ Bt,
                                            const float* __restrict__ bias, void* __restrict__ Cout) {
  const int lane = threadIdx.x & 63;
  const int w = threadIdx.x >> 6;
  const int row0 = blockIdx.x * 64;
  const int colw = w * 64;
  const int lr = lane & 15;
  const int lk = (lane >> 4) * 8;

  const unsigned short* Aptr[4];
  const unsigned short* Bptr[4];
  #pragma unroll
  for (int rt = 0; rt < 4; rt++) {
    int row = row0 + rt * 16 + lr;
    if (row >= NN) row = NN - 1;
    Aptr[rt] = A + (size_t)row * 256 + lk;
  }
  #pragma unroll
  for (int ct = 0; ct < 4; ct++) Bptr[ct] = Bt + (size_t)(colw + ct * 16 + lr) * 256 + lk;

  float4v acc[4][4];
  #pragma unroll
  for (int rt = 0; rt < 4; rt++)
    #pragma unroll
    for (int ct = 0; ct < 4; ct++) acc[rt][ct] = (float4v){0.f, 0.f, 0.f, 0.f};

  for (int ks = 0; ks < 256; ks += 32) {
    short8v a[4], b[4];
    #pragma unroll
    for (int rt = 0; rt < 4; rt++) a[rt] = *reinterpret_cast<const short8v*>(Aptr[rt] + ks);
    #pragma unroll
    for (int ct = 0; ct < 4; ct++) b[ct] = *reinterpret_cast<const short8v*>(Bptr[ct] + ks);
    #pragma unroll
    for (int rt = 0; rt < 4; rt++)
      #pragma unroll
      for (int ct = 0; ct < 4; ct++)
        acc[rt][ct] = __builtin_amdgcn_mfma_f32_16x16x32_bf16(a[rt], b[ct], acc[rt][ct], 0, 0, 0);
  }

  #pragma unroll
  for (int rt = 0; rt < 4; rt++) {
    #pragma unroll
    for (int ct = 0; ct < 4; ct++) {
      const int col = colw + ct * 16 + lr;
      const float bv = ADD_BIAS ? bias[col] : 0.f;
      #pragma unroll
      for (int r = 0; r < 4; r++) {
        const int row = row0 + rt * 16 + (lane >> 4) * 4 + r;
        if (row < NN) {
          float v = acc[rt][ct][r] + bv;
          if (OUT_BF16)
            ((unsigned short*)Cout)[(size_t)row * 256 + col] = f2bf(v);
          else
            ((float*)Cout)[(size_t)row * 256 + col] = v;
        }
      }
    }
  }
}

// ---------------- aggregation: one wave per node, 16 edges in flight ----------------
__global__ __launch_bounds__(256) void k_agg(const unsigned short* __restrict__ P,
                                             const int* __restrict__ offs, const int* __restrict__ srcp,
                                             const float4* __restrict__ wperm, const float* __restrict__ b1,
                                             unsigned short* __restrict__ Rb) {
  const int lane = threadIdx.x & 63;
  const int wid = threadIdx.x >> 6;
  const int i = blockIdx.x * 4 + wid;  // grid = NN/4 exactly
  const int half = lane >> 5;
  const int l32 = lane & 31;
  const int col0 = l32 * 8;
  const int c = l32 >> 3;

  const int es = offs[i], ee = offs[i + 1];
  float acc[8];
  #pragma unroll
  for (int j = 0; j < 8; j++) acc[j] = 0.f;

  for (int base = es; base < ee; base += 16) {
    int sq[8];
    float wq[8];
    #pragma unroll
    for (int q = 0; q < 8; q++) {
      int e = base + 2 * q + half;
      bool valid = e < ee;
      int ec = valid ? e : (NE - 1);
      sq[q] = srcp[ec];
      float4 w4 = wperm[ec];
      float wv = (c == 0) ? w4.x : (c == 1) ? w4.y : (c == 2) ? w4.z : w4.w;
      wq[q] = valid ? wv : 0.f;
    }
    short8v pq[8];
    #pragma unroll
    for (int q = 0; q < 8; q++)
      pq[q] = *reinterpret_cast<const short8v*>(P + (size_t)sq[q] * 256 + col0);
    #pragma unroll
    for (int q = 0; q < 8; q++)
      #pragma unroll
      for (int j = 0; j < 8; j++)
        acc[j] = fmaf(wq[q], bf2f((unsigned short)pq[q][j]), acc[j]);
  }

  #pragma unroll
  for (int j = 0; j < 8; j++) acc[j] += __shfl_xor(acc[j], 32);

  if (half == 0) {
    short8v ps = *reinterpret_cast<const short8v*>(P + (size_t)i * 256 + col0);
    float4 b4a = *reinterpret_cast<const float4*>(b1 + col0);
    float4 b4b = *reinterpret_cast<const float4*>(b1 + col0 + 4);
    float bb[8] = {b4a.x, b4a.y, b4a.z, b4a.w, b4b.x, b4b.y, b4b.z, b4b.w};
    short8v out;
    #pragma unroll
    for (int j = 0; j < 8; j++) {
      float r = bf2f((unsigned short)ps[j]) + acc[j] + bb[j];
      out[j] = (short)f2bf(r > 0.f ? r : 0.f);
    }
    *reinterpret_cast<short8v*>(Rb + (size_t)i * 256 + col0) = out;
  }
}

// ---------------- block-diag K=64 GEMM: stats-only pass (no b2: BN cancels it) ----------------
__global__ __launch_bounds__(256) void k_bd_stats(const unsigned short* __restrict__ A,
                                                  const unsigned short* __restrict__ Wz,
                                                  float* __restrict__ bnsum, float* __restrict__ bnsq) {
  const int lane = threadIdx.x & 63;
  const int c = threadIdx.x >> 6;
  const int row0 = blockIdx.x * 64;
  const int lr = lane & 15;
  const int lk = (lane >> 4) * 8;

  const unsigned short* Aptr[4];
  #pragma unroll
  for (int rt = 0; rt < 4; rt++) {
    int row = row0 + rt * 16 + lr;
    if (row >= NN) row = NN - 1;
    Aptr[rt] = A + (size_t)row * 256 + c * 64 + lk;
  }

  float4v acc[4][4];
  #pragma unroll
  for (int rt = 0; rt < 4; rt++)
    #pragma unroll
    for (int ct = 0; ct < 4; ct++) acc[rt][ct] = (float4v){0.f, 0.f, 0.f, 0.f};

  #pragma unroll
  for (int ks = 0; ks < 64; ks += 32) {
    short8v a[4], b[4];
    #pragma unroll
    for (int rt = 0; rt < 4; rt++) a[rt] = *reinterpret_cast<const short8v*>(Aptr[rt] + ks);
    #pragma unroll
    for (int ct = 0; ct < 4; ct++)
      b[ct] = *reinterpret_cast<const short8v*>(Wz + (size_t)c * 4096 + (ct * 16 + lr) * 64 + ks + lk);
    #pragma unroll
    for (int rt = 0; rt < 4; rt++)
      #pragma unroll
      for (int ct = 0; ct < 4; ct++)
        acc[rt][ct] = __builtin_amdgcn_mfma_f32_16x16x32_bf16(a[rt], b[ct], acc[rt][ct], 0, 0, 0);
  }

  #pragma unroll
  for (int ct = 0; ct < 4; ct++) {
    const int col = c * 64 + ct * 16 + lr;
    float s1 = 0.f, s2 = 0.f;
    #pragma unroll
    for (int rt = 0; rt < 4; rt++) {
      #pragma unroll
      for (int r = 0; r < 4; r++) {
        const int row = row0 + rt * 16 + (lane >> 4) * 4 + r;
        if (row < NN) {
          float v = acc[rt][ct][r];
          s1 += v;
          s2 += v * v;
        }
      }
    }
    s1 += __shfl_xor(s1, 16); s1 += __shfl_xor(s1, 32);
    s2 += __shfl_xor(s2, 16); s2 += __shfl_xor(s2, 32);
    if (lane < 16) {
      atomicAdd(&bnsum[col], s1);
      atomicAdd(&bnsq[col], s2);
    }
  }
}

// ---------------- block-diag K=64 GEMM: recompute + BN + relu; optional fused P2 ----------------
template <int WITH_P2>
__global__ __launch_bounds__(256) void k_bd_bn(const unsigned short* __restrict__ A,
                                               const unsigned short* __restrict__ Wz,
                                               const float* __restrict__ bnsum, const float* __restrict__ bnsq,
                                               const float* __restrict__ g, const float* __restrict__ bt,
                                               const unsigned short* __restrict__ Wp,
                                               float* __restrict__ Hout, unsigned short* __restrict__ P2out) {
  __shared__ __align__(16) unsigned short h_lds[64][264];  // stride 528B: 16B-aligned, ~2-way banks
  const int lane = threadIdx.x & 63;
  const int c = threadIdx.x >> 6;
  const int row0 = blockIdx.x * 64;
  const int lr = lane & 15;
  const int lk = (lane >> 4) * 8;
  const int rbase = (lane >> 4) * 4;

  const unsigned short* Aptr[4];
  #pragma unroll
  for (int rt = 0; rt < 4; rt++) {
    int row = row0 + rt * 16 + lr;
    if (row >= NN) row = NN - 1;
    Aptr[rt] = A + (size_t)row * 256 + c * 64 + lk;
  }

  float4v acc[4][4];
  #pragma unroll
  for (int rt = 0; rt < 4; rt++)
    #pragma unroll
    for (int ct = 0; ct < 4; ct++) acc[rt][ct] = (float4v){0.f, 0.f, 0.f, 0.f};

  #pragma unroll
  for (int ks = 0; ks < 64; ks += 32) {
    short8v a[4], b[4];
    #pragma unroll
    for (int rt = 0; rt < 4; rt++) a[rt] = *reinterpret_cast<const short8v*>(Aptr[rt] + ks);
    #pragma unroll
    for (int ct = 0; ct < 4; ct++)
      b[ct] = *reinterpret_cast<const short8v*>(Wz + (size_t)c * 4096 + (ct * 16 + lr) * 64 + ks + lk);
    #pragma unroll
    for (int rt = 0; rt < 4; rt++)
      #pragma unroll
      for (int ct = 0; ct < 4; ct++)
        acc[rt][ct] = __builtin_amdgcn_mfma_f32_16x16x32_bf16(a[rt], b[ct], acc[rt][ct], 0, 0, 0);
  }

  // BN scale/shift from stats (b2 cancels in BN)
  float sc[4], sh[4];
  #pragma unroll
  for (int ct = 0; ct < 4; ct++) {
    const int t = c * 64 + ct * 16 + lr;
    float mu = bnsum[t] * (1.f / NN);
    float var = bnsq[t] * (1.f / NN) - mu * mu;
    var = var > 0.f ? var : 0.f;
    float rs = rsqrtf(var + 1e-5f);
    sc[ct] = g[t] * rs;
    sh[ct] = bt[t] - mu * sc[ct];
  }

  #pragma unroll
  for (int rt = 0; rt < 4; rt++) {
    #pragma unroll
    for (int ct = 0; ct < 4; ct++) {
      const int col = c * 64 + ct * 16 + lr;
      #pragma unroll
      for (int r = 0; r < 4; r++) {
        const int rowl = rt * 16 + rbase + r;
        const int row = row0 + rowl;
        float h = fmaf(acc[rt][ct][r], sc[ct], sh[ct]);
        h = h > 0.f ? h : 0.f;
        if (row < NN) Hout[(size_t)row * 256 + col] = h;
        if (WITH_P2) h_lds[rowl][col] = f2bf(h);
      }
    }
  }

  if (WITH_P2) {
    __syncthreads();
    float4v acc2[4][4];
    #pragma unroll
    for (int rt = 0; rt < 4; rt++)
      #pragma unroll
      for (int ct = 0; ct < 4; ct++) acc2[rt][ct] = (float4v){0.f, 0.f, 0.f, 0.f};
    #pragma unroll
    for (int ks = 0; ks < 64; ks += 32) {
      short8v a[4], b[4];
      #pragma unroll
      for (int rt = 0; rt < 4; rt++)
        a[rt] = *reinterpret_cast<const short8v*>(&h_lds[rt * 16 + lr][c * 64 + ks + lk]);
      #pragma unroll
      for (int ct = 0; ct < 4; ct++)
        b[ct] = *reinterpret_cast<const short8v*>(Wp + (size_t)c * 4096 + (ct * 16 + lr) * 64 + ks + lk);
      #pragma unroll
      for (int rt = 0; rt < 4; rt++)
        #pragma unroll
        for (int ct = 0; ct < 4; ct++)
          acc2[rt][ct] = __builtin_amdgcn_mfma_f32_16x16x32_bf16(a[rt], b[ct], acc2[rt][ct], 0, 0, 0);
    }
    #pragma unroll
    for (int rt = 0; rt < 4; rt++) {
      #pragma unroll
      for (int ct = 0; ct < 4; ct++) {
        const int col = c * 64 + ct * 16 + lr;
        #pragma unroll
        for (int r = 0; r < 4; r++) {
          const int row = row0 + rt * 16 + rbase + r;
          if (row < NN) P2out[(size_t)row * 256 + col] = f2bf(acc2[rt][ct][r]);
        }
      }
    }
  }
}

// ---------------- launch ----------------

extern "C" void kernel_launch(void* const* d_in, const int* in_sizes, int n_in,
                              void* d_out, int out_size, void* d_ws, size_t ws_size,
                              hipStream_t stream) {
  const float* x    = (const float*)d_in[0];
  const int*   ei   = (const int*)d_in[1];
  const float* ew   = (const float*)d_in[2];
  const float* W1_0 = (const float*)d_in[3];
  const float* b1_0 = (const float*)d_in[4];
  const float* W2_0 = (const float*)d_in[5];
  // b2 unused: BatchNorm cancels the pre-BN bias exactly
  const float* g0   = (const float*)d_in[7];
  const float* bt0  = (const float*)d_in[8];
  const float* W1_1 = (const float*)d_in[9];
  const float* b1_1 = (const float*)d_in[10];
  const float* W2_1 = (const float*)d_in[11];
  const float* g1   = (const float*)d_in[13];
  const float* bt1  = (const float*)d_in[14];
  const float* encW = (const float*)d_in[15];
  const float* encb = (const float*)d_in[16];

  const int* srcA = ei;
  const int* dstA = ei + NE;

  float* out_enc = (float*)d_out;
  float* out1 = out_enc + (size_t)NN * FDIM;
  float* out2 = out1 + (size_t)NN * FDIM;

  // enc output region (written last) hosts P (bf16) and Rb (bf16): 25.6+25.6MB
  unsigned short* Pbf = (unsigned short*)out_enc;
  unsigned short* Rb  = Pbf + (size_t)NN * FDIM;

  char* wp = (char*)d_ws;
  auto carve = [&](size_t bytes) {
    char* r = wp;
    wp += (bytes + 255) & ~(size_t)255;
    return r;
  };
  int*   deg    = (int*)carve((size_t)NN * 4);
  int*   offs   = (int*)carve((size_t)(NN + 1) * 4);
  int*   fillp  = (int*)carve((size_t)NN * 4);
  int*   srcp   = (int*)carve((size_t)NE * 4);
  float4* wperm = (float4*)carve((size_t)NE * 16);
  int*   partial = (int*)carve(SCAN_BLOCKS * 4);
  float* bnsum0 = (float*)carve(256 * 4);
  float* bnsq0  = (float*)carve(256 * 4);
  float* bnsum1 = (float*)carve(256 * 4);
  float* bnsq1  = (float*)carve(256 * 4);
  unsigned short* Bt1  = (unsigned short*)carve(256 * 256 * 2);
  unsigned short* BtE  = (unsigned short*)carve(256 * 256 * 2);
  unsigned short* Wb11 = (unsigned short*)carve(4 * 64 * 64 * 2);
  unsigned short* Wb20 = (unsigned short*)carve(4 * 64 * 64 * 2);
  unsigned short* Wb21 = (unsigned short*)carve(4 * 64 * 64 * 2);
  unsigned short* xb   = (unsigned short*)carve((size_t)NN * FDIM * 2);

  hipMemsetAsync(deg, 0, (size_t)NN * 4, stream);
  hipMemsetAsync(bnsum0, 0, 4 * 1024, stream);  // bnsum0,bnsq0,bnsum1,bnsq1 contiguous

  // CSR build (parallel scan) + direct fill of src ids and permuted weights
  k_hist<<<(NE + 255) / 256, 256, 0, stream>>>(dstA, deg);
  k_scan_a<<<SCAN_BLOCKS, 256, 0, stream>>>(deg, partial);
  k_scan_b<<<1, 256, 0, stream>>>(partial, offs);
  k_scan_c<<<SCAN_BLOCKS, 256, 0, stream>>>(deg, partial, offs, fillp);
  k_fillperm<<<(NE + 255) / 256, 256, 0, stream>>>(srcA, dstA, ew, fillp, srcp, wperm);

  // bf16 prep
  k_wprep<<<256, 256, 0, stream>>>(W1_0, encW, W1_1, W2_0, W2_1, Bt1, BtE, Wb11, Wb20, Wb21);
  k_xprep<<<(NN * 64 + 255) / 256, 256, 0, stream>>>(x, xb);

  const int MMG = (NN + 63) / 64;

  // layer 1
  k_mm<1, 0><<<MMG, 256, 0, stream>>>(xb, Bt1, nullptr, Pbf);
  k_agg<<<NN / 4, 256, 0, stream>>>(Pbf, offs, srcp, wperm, b1_0, Rb);
  k_bd_stats<<<MMG, 256, 0, stream>>>(Rb, Wb20, bnsum0, bnsq0);
  k_bd_bn<1><<<MMG, 256, 0, stream>>>(Rb, Wb20, bnsum0, bnsq0, g0, bt0, Wb11, out1, Pbf);

  // layer 2 (P2 already in Pbf)
  k_agg<<<NN / 4, 256, 0, stream>>>(Pbf, offs, srcp, wperm, b1_1, Rb);
  k_bd_stats<<<MMG, 256, 0, stream>>>(Rb, Wb21, bnsum1, bnsq1);
  k_bd_bn<0><<<MMG, 256, 0, stream>>>(Rb, Wb21, bnsum1, bnsq1, g1, bt1, nullptr, out2, nullptr);

  // encoder last (overwrites Pbf/Rb scratch with final enc output)
  k_mm<0, 1><<<MMG, 256, 0, stream>>>(xb, BtE, encb, out_enc);
}